// Round 5
// baseline (328.570 us; speedup 1.0000x reference)
//
#include <hip/hip_runtime.h>

#define NB 32
#define NC 3
#define NK 64
#define KS 7
#define IH 224
#define IW 224
#define OH 218
#define OW 218
#define OHW (OH * OW)
#define RG 4          // output rows per group
#define GROUPS 4      // groups per block -> 16 rows/block
#define NKB 32        // k's per block (k-split)

typedef float  f32x4 __attribute__((ext_vector_type(4)));
typedef short  s16x8 __attribute__((ext_vector_type(8)));
typedef unsigned long long u64;

static __device__ __forceinline__ unsigned short f2bf(float f) {
  unsigned int u = __float_as_uint(f);
  u += 0x7FFFu + ((u >> 16) & 1u);
  return (unsigned short)(u >> 16);
}

// XOR block-swizzle on a 32-u16 (64 B) row: 16B-block ^= (row>>1)&3.
static __device__ __forceinline__ int swz(int r, int ci) {
  return (((ci >> 3) ^ ((r >> 1) & 3)) << 3) | (ci & 7);
}

// ---------------- prep kernels ----------------

// fused: x -> bf16, s = sum_c x^2 (LDS), row box -> t[b][h][ow]
__global__ void k_prep_xrow(const float* __restrict__ x, unsigned short* __restrict__ xb,
                            float* __restrict__ t) {
  __shared__ float s_lds[IW];
  const int n  = blockIdx.x;          // NB*IH
  const int b  = n / IH;
  const int h  = n - b * IH;
  const int px = threadIdx.x;
  if (px < IW) {
    float acc = 0.f;
#pragma unroll
    for (int c = 0; c < NC; ++c) {
      size_t idx = ((size_t)(b * NC + c) * IH + h) * IW + px;
      float v = x[idx];
      xb[idx] = f2bf(v);
      acc += v * v;
    }
    s_lds[px] = acc;
  }
  __syncthreads();
  if (px < OW) {
    float acc = 0.f;
#pragma unroll
    for (int j = 0; j < KS; ++j) acc += s_lds[px + j];
    t[(size_t)(b * IH + h) * OW + px] = acc;
  }
}

// col box: x2[b][oh][ow] = sum_{i<7} t[b][oh+i][ow]
__global__ void k_colbox(const float* __restrict__ t, float* __restrict__ x2) {
  int n = blockIdx.x * 256 + threadIdx.x;            // NB*OH*OW
  if (n >= NB * OH * OW) return;
  int b = n / (OH * OW);
  int r = n - b * (OH * OW);
  int oh = r / OW;
  int ow = r - oh * OW;
  const float* col = t + (size_t)(b * IH + oh) * OW + ow;
  float acc = 0.f;
#pragma unroll
  for (int i = 0; i < KS; ++i) acc += col[i * OW];
  x2[n] = acc;
}

// WTg[row=j*64+k][ci'(swizzled, 32)] = bf16(memes[k][c][i][j]); zeros at ci>=21.
// 64 blocks (one per k) x 192 threads (one per (c,i,j)).
__global__ void k_prep_w(const float* __restrict__ memes, unsigned short* __restrict__ WTg,
                         float* __restrict__ m2inv) {
  __shared__ float red[3];
  const int k = blockIdx.x, t = threadIdx.x;
  float v = 0.f;
  if (t < 147) v = memes[k * 147 + t];
  float s = v * v;
#pragma unroll
  for (int sh = 32; sh > 0; sh >>= 1) s += __shfl_down(s, sh, 64);
  if ((t & 63) == 0) red[t >> 6] = s;
  __syncthreads();
  if (t == 0) m2inv[k] = 1.0f / (red[0] + red[1] + red[2]);
  if (t < 147) {
    int c = t / 49, rem = t - 49 * c, i = rem / 7, j = rem - 7 * i;
    int row = j * NK + k;
    WTg[row * 32 + swz(row, c * 7 + i)] = f2bf(v);
  }
  for (int idx = t; idx < 7 * 11; idx += 192) {
    int j = idx / 11, ci = 21 + (idx - 11 * j);
    int row = j * NK + k;
    WTg[row * 32 + swz(row, ci)] = 0;
  }
}

// ---------------- staging (issue-early / write-late) ----------------
// One group = RG rows x 21 ci x 72 t (4-at-a-time u64) = 1512 slots over 256 thr * 6.
static __device__ __forceinline__ void xt_issue(u64 v[6],
    const unsigned short* __restrict__ xb, int b, int oh0, int ow0, int tid) {
#pragma unroll
  for (int m = 0; m < 6; ++m) {
    int idx = tid + 256 * m;
    u64 val = 0;
    if (idx < 1512) {
      int tq = idx % 18;
      int rc = idx / 18;
      int ci = rc % 21;
      int r  = rc / 21;
      int c  = ci / 7;
      int i  = ci - 7 * c;
      // no bounds guards: overreads stay inside ws (finite data), results dumped
      val = *(const u64*)&xb[((size_t)(b * NC + c) * IH + (oh0 + r + i)) * IW + ow0 + 4 * tq];
    }
    v[m] = val;
  }
}

static __device__ __forceinline__ void xt_write(unsigned short* __restrict__ XT,
    const u64 v[6], int tid) {
#pragma unroll
  for (int m = 0; m < 6; ++m) {
    int idx = tid + 256 * m;
    if (idx < 1512) {
      int tq = idx % 18;
      int rc = idx / 18;
      int ci = rc % 21;
      int r  = rc / 21;
#pragma unroll
      for (int e = 0; e < 4; ++e) {
        int t = 4 * tq + e;
        XT[r * 2304 + t * 32 + swz(t, ci)] = (unsigned short)(v[m] >> (16 * e));
      }
    }
  }
}

// ---------------- main MFMA kernel ----------------
// Block: 256 thr (4 waves), target 5 blocks/CU (LDS = 32768 exactly).
// Tile: one b, one k-half (32 k), 64 ow, 16 oh rows in 4 groups of RG=4.
__global__ __launch_bounds__(256, 5) void k_main(
    const unsigned short* __restrict__ xb, const float* __restrict__ x2g,
    const unsigned short* __restrict__ WTg, const float* __restrict__ m2inv,
    float* __restrict__ out, float* __restrict__ dump) {
  __shared__ __align__(16) unsigned short WTl[KS * NKB * 32];   // 14336 B
  __shared__ __align__(16) unsigned short XTl[RG * 72 * 32];    // 18432 B

  const int tid  = threadIdx.x;
  const int w    = tid >> 6;
  const int lane = tid & 63;
  const int lg   = lane >> 4;
  const int lr   = lane & 15;

  const int ow0 = blockIdx.x * 64;
  const int ohb = blockIdx.y * (RG * GROUPS);
  const int kh  = blockIdx.z & 1;
  const int b   = blockIdx.z >> 1;

  // WT k-half: linear async copy global->LDS (14 x 1024 B chunks)
  for (int ch = w; ch < 14; ch += 4) {
    const int j = ch >> 1, hf = ch & 1;
    const unsigned short* g = WTg + j * 2048 + kh * 1024 + hf * 512 + lane * 8;
    unsigned short* l = WTl + ch * 512;
    __builtin_amdgcn_global_load_lds((const __attribute__((address_space(1))) void*)g,
                                     (__attribute__((address_space(3))) void*)l, 16, 0, 0);
  }

  // per-lane m2 (8 regs), L2-hot
  float m2v[8];
  {
    const float* mp = m2inv + kh * 32 + 4 * lg;
#pragma unroll
    for (int rr = 0; rr < 4; ++rr) { m2v[rr] = mp[rr]; m2v[4 + rr] = mp[16 + rr]; }
  }

  // zero ALL pad lanes ci=21..31 (physical: block-2 tail + whole block 3, per-row
  // swizzled). MFMA reads every ci lane; pads must be finite (0*NaN = NaN!).
  for (int idx = tid; idx < RG * 72; idx += 256) {
    int r = idx / 72, t = idx - 72 * r;
    unsigned short* row = &XTl[r * 2304 + t * 32];
    const int m = (t >> 1) & 3;
    *(uint4*)&row[(3 ^ m) << 3] = (uint4){0, 0, 0, 0};   // ci 24..31
    const int b2 = (2 ^ m) << 3;                          // ci 21..23 (block 2, low3 unswizzled)
    row[b2 + 5] = 0; row[b2 + 6] = 0; row[b2 + 7] = 0;
  }

  u64 s0[6];
  xt_issue(s0, xb, b, ohb, ow0, tid);
  xt_write(XTl, s0, tid);
  asm volatile("s_waitcnt vmcnt(0) lgkmcnt(0)" ::: "memory");   // WT lds + XT writes
  __builtin_amdgcn_s_barrier();

  const int px  = w * 16 + lr;
  const int ow  = ow0 + px;
  const int swa = (lr >> 1) & 3;

#pragma unroll
  for (int g = 0; g < GROUPS; ++g) {
    const int oh0 = ohb + g * RG;

    u64 sN[6];
    if (g + 1 < GROUPS) xt_issue(sN, xb, b, oh0 + RG, ow0, tid);  // fly over MFMAs

    f32x4 acc[RG][2];
#pragma unroll
    for (int r = 0; r < RG; ++r) {
      acc[r][0] = (f32x4){0.f, 0.f, 0.f, 0.f};
      acc[r][1] = (f32x4){0.f, 0.f, 0.f, 0.f};
    }

#pragma unroll
    for (int j = 0; j < KS; ++j) {
      const unsigned short* ab = WTl + j * 1024 + lr * 32 + ((lg ^ swa) << 3);
      s16x8 a0 = *(const s16x8*)&ab[0];
      s16x8 a1 = *(const s16x8*)&ab[512];
      const int t = px + j;
      const int boff = t * 32 + ((lg ^ ((t >> 1) & 3)) << 3);
#pragma unroll
      for (int r = 0; r < RG; ++r) {
        s16x8 bf_ = *(const s16x8*)&XTl[r * 2304 + boff];
        acc[r][0] = __builtin_amdgcn_mfma_f32_16x16x32_bf16(a0, bf_, acc[r][0], 0, 0, 0);
        acc[r][1] = __builtin_amdgcn_mfma_f32_16x16x32_bf16(a1, bf_, acc[r][1], 0, 0, 0);
      }
    }

    // branchless epilogue: invalid lanes store to dump (ks=0 collapses k-stride)
#pragma unroll
    for (int r = 0; r < RG; ++r) {
      const int oh = oh0 + r;
      const bool ok = (ow < OW) && (oh < OH);
      const int ohc = ok ? oh : 0;
      const int owc = ok ? ow : 0;
      const float x2v = x2g[(size_t)(b * OH + ohc) * OW + owc];
      float* ob = ok ? out + ((size_t)(b * NK + kh * 32) * OH + oh) * OW + ow
                     : dump + tid;
      const size_t ks = ok ? (size_t)OHW : 0;
#pragma unroll
      for (int rr = 0; rr < 4; ++rr) {
        const int k0 = 4 * lg + rr;
        ob[(size_t)k0 * ks]        = (x2v - 2.0f * acc[r][0][rr]) * m2v[rr]     + 1.0f;
        ob[(size_t)(k0 + 16) * ks] = (x2v - 2.0f * acc[r][1][rr]) * m2v[4 + rr] + 1.0f;
      }
    }

    if (g + 1 < GROUPS) {
      asm volatile("s_waitcnt lgkmcnt(0)" ::: "memory");  // all waves' ds_reads done
      __builtin_amdgcn_s_barrier();
      xt_write(XTl, sN, tid);                             // vmcnt for sN counted by compiler
      asm volatile("s_waitcnt lgkmcnt(0)" ::: "memory");
      __builtin_amdgcn_s_barrier();
    }
  }
}

// ---------------- launch ----------------
extern "C" void kernel_launch(void* const* d_in, const int* in_sizes, int n_in,
                              void* d_out, int out_size, void* d_ws, size_t ws_size,
                              hipStream_t stream) {
  const float* x     = (const float*)d_in[0];   // [32,3,224,224]
  const float* memes = (const float*)d_in[1];   // [64,3,7,7]
  float* out = (float*)d_out;                   // [32,64,218,218]

  char* ws = (char*)d_ws;
  unsigned short* xb  = (unsigned short*)(ws);                 // 9,633,792 B
  float* t            = (float*)(ws + 9633792);                // 6,250,496 B
  float* x2           = (float*)(ws + 15884288);               // 6,083,072 B
  unsigned short* WTg = (unsigned short*)(ws + 21967360);      // 28,672 B
  float* m2inv        = (float*)(ws + 21996032);               // 256 B
  float* dump         = (float*)(ws + 21996544);               // scratch sink

  (void)in_sizes; (void)n_in; (void)out_size; (void)ws_size;

  k_prep_xrow<<<NB * IH, 256, 0, stream>>>(x, xb, t);
  k_colbox<<<(NB * OH * OW + 255) / 256, 256, 0, stream>>>(t, x2);
  k_prep_w<<<NK, 192, 0, stream>>>(memes, WTg, m2inv);

  dim3 grid((OW + 63) / 64, (OH + RG * GROUPS - 1) / (RG * GROUPS), NB * 2);
  k_main<<<grid, 256, 0, stream>>>(xb, x2, WTg, m2inv, out, dump);
}

// Round 6
// 188.984 us; speedup vs baseline: 1.7386x; 1.7386x over previous
//
#include <hip/hip_runtime.h>

#define NB 32
#define NC 3
#define NK 64
#define KS 7
#define IH 224
#define IW 224
#define OH 218
#define OW 218
#define OHW (OH * OW)
#define ROWS 8        // output rows per block (per-row double-buffered)

typedef float  f32x4 __attribute__((ext_vector_type(4)));
typedef short  s16x8 __attribute__((ext_vector_type(8)));
typedef unsigned long long u64;

static __device__ __forceinline__ unsigned short f2bf(float f) {
  unsigned int u = __float_as_uint(f);
  u += 0x7FFFu + ((u >> 16) & 1u);
  return (unsigned short)(u >> 16);
}

// XOR block-swizzle on a 32-u16 (64 B) row: 16B-block ^= (row>>1)&3.
static __device__ __forceinline__ int swz(int r, int ci) {
  return (((ci >> 3) ^ ((r >> 1) & 3)) << 3) | (ci & 7);
}

// ---------------- prep kernels ----------------

// fused: x -> bf16, s = sum_c x^2 (LDS), row box -> t[b][h][ow]
__global__ void k_prep_xrow(const float* __restrict__ x, unsigned short* __restrict__ xb,
                            float* __restrict__ t) {
  __shared__ float s_lds[IW];
  const int n  = blockIdx.x;          // NB*IH
  const int b  = n / IH;
  const int h  = n - b * IH;
  const int px = threadIdx.x;
  if (px < IW) {
    float acc = 0.f;
#pragma unroll
    for (int c = 0; c < NC; ++c) {
      size_t idx = ((size_t)(b * NC + c) * IH + h) * IW + px;
      float v = x[idx];
      xb[idx] = f2bf(v);
      acc += v * v;
    }
    s_lds[px] = acc;
  }
  __syncthreads();
  if (px < OW) {
    float acc = 0.f;
#pragma unroll
    for (int j = 0; j < KS; ++j) acc += s_lds[px + j];
    t[(size_t)(b * IH + h) * OW + px] = acc;
  }
}

// col box: x2[b][oh][ow] = sum_{i<7} t[b][oh+i][ow]
__global__ void k_colbox(const float* __restrict__ t, float* __restrict__ x2) {
  int n = blockIdx.x * 256 + threadIdx.x;            // NB*OH*OW
  if (n >= NB * OH * OW) return;
  int b = n / (OH * OW);
  int r = n - b * (OH * OW);
  int oh = r / OW;
  int ow = r - oh * OW;
  const float* col = t + (size_t)(b * IH + oh) * OW + ow;
  float acc = 0.f;
#pragma unroll
  for (int i = 0; i < KS; ++i) acc += col[i * OW];
  x2[n] = acc;
}

// WTg[row=j*64+k][ci'(swizzled, 32)] = bf16(memes[k][c][i][j]); zeros at ci>=21.
__global__ void k_prep_w(const float* __restrict__ memes, unsigned short* __restrict__ WTg,
                         float* __restrict__ m2inv) {
  __shared__ float red[3];
  const int k = blockIdx.x, t = threadIdx.x;
  float v = 0.f;
  if (t < 147) v = memes[k * 147 + t];
  float s = v * v;
#pragma unroll
  for (int sh = 32; sh > 0; sh >>= 1) s += __shfl_down(s, sh, 64);
  if ((t & 63) == 0) red[t >> 6] = s;
  __syncthreads();
  if (t == 0) m2inv[k] = 1.0f / (red[0] + red[1] + red[2]);
  if (t < 147) {
    int c = t / 49, rem = t - 49 * c, i = rem / 7, j = rem - 7 * i;
    int row = j * NK + k;
    WTg[row * 32 + swz(row, c * 7 + i)] = f2bf(v);
  }
  for (int idx = t; idx < 7 * 11; idx += 192) {
    int j = idx / 11, ci = 21 + (idx - 11 * j);
    int row = j * NK + k;
    WTg[row * 32 + swz(row, ci)] = 0;
  }
}

// ---------------- per-row staging (issue-early / write-late) ----------------
// One row = 21 ci x 18 tq (u64 = 4 px) = 378 slots over 256 threads * 2.
static __device__ __forceinline__ void xt_issue(u64 v[2],
    const unsigned short* __restrict__ xb, int b, int oh, int ow0, int tid) {
#pragma unroll
  for (int m = 0; m < 2; ++m) {
    int idx = tid + 256 * m;
    u64 val = 0;
    if (idx < 378) {
      int tq = idx % 18;
      int ci = idx / 18;
      int c  = ci / 7;
      int i  = ci - 7 * c;
      // unguarded: overreads stay inside ws (finite bits), feed only dumped lanes
      val = *(const u64*)&xb[((size_t)(b * NC + c) * IH + oh + i) * IW + ow0 + 4 * tq];
    }
    v[m] = val;
  }
}

static __device__ __forceinline__ void xt_write(unsigned short* __restrict__ XT,
    const u64 v[2], int tid) {
#pragma unroll
  for (int m = 0; m < 2; ++m) {
    int idx = tid + 256 * m;
    if (idx < 378) {
      int tq = idx % 18;
      int ci = idx / 18;
#pragma unroll
      for (int e = 0; e < 4; ++e) {
        int t = 4 * tq + e;
        XT[t * 32 + swz(t, ci)] = (unsigned short)(v[m] >> (16 * e));
      }
    }
  }
}

// ---------------- main MFMA kernel ----------------
// Block: 256 thr (4 waves), 4 blocks/CU (LDS 38.4 KB). Tile: one b, all 64 k,
// 64 ow, 8 oh rows; per-row double-buffered XT, ONE barrier per row, stores
// never vmcnt-drained inside the loop.
__global__ __launch_bounds__(256, 4) void k_main(
    const unsigned short* __restrict__ xb, const float* __restrict__ x2g,
    const unsigned short* __restrict__ WTg, const float* __restrict__ m2inv,
    float* __restrict__ out, float* __restrict__ dump) {
  __shared__ __align__(16) unsigned short WTl[KS * NK * 32];   // 28672 B
  __shared__ __align__(16) unsigned short XTl[2][72 * 32];     // 9216 B

  const int tid  = threadIdx.x;
  const int w    = tid >> 6;
  const int lane = tid & 63;
  const int lg   = lane >> 4;
  const int lr   = lane & 15;

  const int ow0 = blockIdx.x * 64;
  const int ohb = blockIdx.y * ROWS;
  const int b   = blockIdx.z;

  // WT: linear async copy global->LDS (28 x 1024 B)
  for (int ch = w; ch < 28; ch += 4) {
    const unsigned short* g = WTg + ch * 512 + lane * 8;
    unsigned short* l = WTl + ch * 512;
    __builtin_amdgcn_global_load_lds((const __attribute__((address_space(1))) void*)g,
                                     (__attribute__((address_space(3))) void*)l, 16, 0, 0);
  }

  // m2 in 16 regs: k0 = 16q + 4lg + rr
  f32x4 m2r[4];
#pragma unroll
  for (int q = 0; q < 4; ++q) m2r[q] = *(const f32x4*)&m2inv[16 * q + 4 * lg];

  // zero pad lanes ci=21..31 in BOTH buffers (MFMA reads them; 0*NaN=NaN!)
  for (int idx = tid; idx < 2 * 72; idx += 256) {
    int bb = idx / 72, t = idx - 72 * bb;
    unsigned short* row = &XTl[bb][t * 32];
    const int m = (t >> 1) & 3;
    *(uint4*)&row[(3 ^ m) << 3] = (uint4){0, 0, 0, 0};   // ci 24..31
    const int b2 = (2 ^ m) << 3;                          // ci 21..23
    row[b2 + 5] = 0; row[b2 + 6] = 0; row[b2 + 7] = 0;
  }

  u64 s0[2];
  xt_issue(s0, xb, b, ohb, ow0, tid);
  xt_write(&XTl[0][0], s0, tid);
  asm volatile("s_waitcnt vmcnt(0) lgkmcnt(0)" ::: "memory");  // WT lds + XT writes
  __builtin_amdgcn_s_barrier();

  const int px  = w * 16 + lr;
  const int ow  = ow0 + px;
  const int swa = (lr >> 1) & 3;

#pragma unroll 1
  for (int r = 0; r < ROWS; ++r) {
    const int oh = ohb + r;
    const bool more = (r + 1 < ROWS);

    u64 sn[2];
    if (more) xt_issue(sn, xb, b, oh + 1, ow0, tid);   // loads fly over MFMAs

    // x2 early (clamped; invalid lanes dump later)
    const bool ok = (ow < OW) && (oh < OH);
    const float x2v = x2g[(size_t)(b * OH + (ok ? oh : 0)) * OW + (ok ? ow : 0)];

    const unsigned short* XT = &XTl[r & 1][0];
    f32x4 acc[4];
#pragma unroll
    for (int q = 0; q < 4; ++q) acc[q] = (f32x4){0.f, 0.f, 0.f, 0.f};

#pragma unroll
    for (int j = 0; j < KS; ++j) {
      const unsigned short* ab = WTl + j * 2048 + lr * 32 + ((lg ^ swa) << 3);
      s16x8 a0 = *(const s16x8*)&ab[0];
      s16x8 a1 = *(const s16x8*)&ab[512];
      s16x8 a2 = *(const s16x8*)&ab[1024];
      s16x8 a3 = *(const s16x8*)&ab[1536];
      const int t = px + j;
      s16x8 bf_ = *(const s16x8*)&XT[t * 32 + ((lg ^ ((t >> 1) & 3)) << 3)];
      acc[0] = __builtin_amdgcn_mfma_f32_16x16x32_bf16(a0, bf_, acc[0], 0, 0, 0);
      acc[1] = __builtin_amdgcn_mfma_f32_16x16x32_bf16(a1, bf_, acc[1], 0, 0, 0);
      acc[2] = __builtin_amdgcn_mfma_f32_16x16x32_bf16(a2, bf_, acc[2], 0, 0, 0);
      acc[3] = __builtin_amdgcn_mfma_f32_16x16x32_bf16(a3, bf_, acc[3], 0, 0, 0);
    }

    // branchless store: invalid lanes go to dump (ks=0 collapses the k-stride)
    float* ob = ok ? out + ((size_t)(b * NK) * OH + oh) * OW + ow : dump + tid;
    const size_t ks = ok ? (size_t)OHW : 0;
#pragma unroll
    for (int q = 0; q < 4; ++q)
#pragma unroll
      for (int rr = 0; rr < 4; ++rr) {
        const int k0 = 16 * q + 4 * lg + rr;
        ob[(size_t)k0 * ks] = (x2v - 2.0f * acc[q][rr]) * m2r[q][rr] + 1.0f;
      }

    if (more) {
      xt_write(&XTl[(r + 1) & 1][0], sn, tid);  // other-parity buffer: no read hazard
      asm volatile("s_waitcnt lgkmcnt(0)" ::: "memory");
      __builtin_amdgcn_s_barrier();             // single barrier per row
    }
  }
}

// ---------------- launch ----------------
extern "C" void kernel_launch(void* const* d_in, const int* in_sizes, int n_in,
                              void* d_out, int out_size, void* d_ws, size_t ws_size,
                              hipStream_t stream) {
  const float* x     = (const float*)d_in[0];   // [32,3,224,224]
  const float* memes = (const float*)d_in[1];   // [64,3,7,7]
  float* out = (float*)d_out;                   // [32,64,218,218]

  char* ws = (char*)d_ws;
  unsigned short* xb  = (unsigned short*)(ws);                 // 9,633,792 B
  float* t            = (float*)(ws + 9633792);                // 6,250,496 B
  float* x2           = (float*)(ws + 15884288);               // 6,083,072 B
  unsigned short* WTg = (unsigned short*)(ws + 21967360);      // 28,672 B
  float* m2inv        = (float*)(ws + 21996032);               // 256 B
  float* dump         = (float*)(ws + 21996544);               // scratch sink

  (void)in_sizes; (void)n_in; (void)out_size; (void)ws_size;

  k_prep_xrow<<<NB * IH, 256, 0, stream>>>(x, xb, t);
  k_colbox<<<(NB * OH * OW + 255) / 256, 256, 0, stream>>>(t, x2);
  k_prep_w<<<NK, 192, 0, stream>>>(memes, WTg, m2inv);

  dim3 grid((OW + 63) / 64, (OH + ROWS - 1) / ROWS, NB);
  k_main<<<grid, 256, 0, stream>>>(xb, x2, WTg, m2inv, out, dump);
}

// Round 7
// 159.199 us; speedup vs baseline: 2.0639x; 1.1871x over previous
//
#include <hip/hip_runtime.h>

#define NB 32
#define NC 3
#define NK 64
#define KS 7
#define IH 224
#define IW 224
#define OH 218
#define OW 218
#define OHW (OH * OW)
#define ROWS 8        // output rows per block (per-row double-buffered)

typedef float  f32x4  __attribute__((ext_vector_type(4)));
typedef float  f32x16 __attribute__((ext_vector_type(16)));
typedef short  s16x8  __attribute__((ext_vector_type(8)));
typedef unsigned long long u64;

static __device__ __forceinline__ unsigned short f2bf(float f) {
  unsigned int u = __float_as_uint(f);
  u += 0x7FFFu + ((u >> 16) & 1u);
  return (unsigned short)(u >> 16);
}

// XOR block-swizzle on a 32-u16 (64 B) row: 16B-block ^= (row>>1)&3.
static __device__ __forceinline__ int swz(int r, int ci) {
  return (((ci >> 3) ^ ((r >> 1) & 3)) << 3) | (ci & 7);
}

// ---------------- prep kernels ----------------

// fused: x -> bf16, s = sum_c x^2 (LDS), row box -> t[b][h][ow]
__global__ void k_prep_xrow(const float* __restrict__ x, unsigned short* __restrict__ xb,
                            float* __restrict__ t) {
  __shared__ float s_lds[IW];
  const int n  = blockIdx.x;          // NB*IH
  const int b  = n / IH;
  const int h  = n - b * IH;
  const int px = threadIdx.x;
  if (px < IW) {
    float acc = 0.f;
#pragma unroll
    for (int c = 0; c < NC; ++c) {
      size_t idx = ((size_t)(b * NC + c) * IH + h) * IW + px;
      float v = x[idx];
      xb[idx] = f2bf(v);
      acc += v * v;
    }
    s_lds[px] = acc;
  }
  __syncthreads();
  if (px < OW) {
    float acc = 0.f;
#pragma unroll
    for (int j = 0; j < KS; ++j) acc += s_lds[px + j];
    t[(size_t)(b * IH + h) * OW + px] = acc;
  }
}

// col box: x2[b][oh][ow] = sum_{i<7} t[b][oh+i][ow]
__global__ void k_colbox(const float* __restrict__ t, float* __restrict__ x2) {
  int n = blockIdx.x * 256 + threadIdx.x;            // NB*OH*OW
  if (n >= NB * OH * OW) return;
  int b = n / (OH * OW);
  int r = n - b * (OH * OW);
  int oh = r / OW;
  int ow = r - oh * OW;
  const float* col = t + (size_t)(b * IH + oh) * OW + ow;
  float acc = 0.f;
#pragma unroll
  for (int i = 0; i < KS; ++i) acc += col[i * OW];
  x2[n] = acc;
}

// WTg[row=j*64+k][ci'(swizzled, 32)] = bf16(memes[k][c][i][j]); zeros at ci>=21.
__global__ void k_prep_w(const float* __restrict__ memes, unsigned short* __restrict__ WTg,
                         float* __restrict__ m2inv) {
  __shared__ float red[3];
  const int k = blockIdx.x, t = threadIdx.x;
  float v = 0.f;
  if (t < 147) v = memes[k * 147 + t];
  float s = v * v;
#pragma unroll
  for (int sh = 32; sh > 0; sh >>= 1) s += __shfl_down(s, sh, 64);
  if ((t & 63) == 0) red[t >> 6] = s;
  __syncthreads();
  if (t == 0) m2inv[k] = 1.0f / (red[0] + red[1] + red[2]);
  if (t < 147) {
    int c = t / 49, rem = t - 49 * c, i = rem / 7, j = rem - 7 * i;
    int row = j * NK + k;
    WTg[row * 32 + swz(row, c * 7 + i)] = f2bf(v);
  }
  for (int idx = t; idx < 7 * 11; idx += 192) {
    int j = idx / 11, ci = 21 + (idx - 11 * j);
    int row = j * NK + k;
    WTg[row * 32 + swz(row, ci)] = 0;
  }
}

// ---------------- per-row staging (issue-early / write-late) ----------------
// One row = 21 ci x 18 tq (u64 = 4 px) = 378 slots over 256 threads * 2.
static __device__ __forceinline__ void xt_issue(u64 v[2],
    const unsigned short* __restrict__ xb, int b, int oh, int ow0, int tid) {
#pragma unroll
  for (int m = 0; m < 2; ++m) {
    int idx = tid + 256 * m;
    u64 val = 0;
    if (idx < 378) {
      int tq = idx % 18;
      int ci = idx / 18;
      int c  = ci / 7;
      int i  = ci - 7 * c;
      // unguarded: overreads stay inside ws (finite bits), feed only dumped lanes
      val = *(const u64*)&xb[((size_t)(b * NC + c) * IH + oh + i) * IW + ow0 + 4 * tq];
    }
    v[m] = val;
  }
}

static __device__ __forceinline__ void xt_write(unsigned short* __restrict__ XT,
    const u64 v[2], int tid) {
#pragma unroll
  for (int m = 0; m < 2; ++m) {
    int idx = tid + 256 * m;
    if (idx < 378) {
      int tq = idx % 18;
      int ci = idx / 18;
#pragma unroll
      for (int e = 0; e < 4; ++e) {
        int t = 4 * tq + e;
        XT[t * 32 + swz(t, ci)] = (unsigned short)(v[m] >> (16 * e));
      }
    }
  }
}

// ---------------- main MFMA kernel (32x32x16) ----------------
// Block: 256 thr (4 waves), 4 blocks/CU. Wave = (k-half, px-half) quadrant.
// Store instr = 2 full 128B lines (32 consecutive ow x one k, x2 k's).
// XCD-chunked swizzle: each XCD owns 4 consecutive b's entirely.
__global__ __launch_bounds__(256, 4) void k_main(
    const unsigned short* __restrict__ xb, const float* __restrict__ x2g,
    const unsigned short* __restrict__ WTg, const float* __restrict__ m2inv,
    float* __restrict__ out, float* __restrict__ dump) {
  __shared__ __align__(16) unsigned short WTl[KS * NK * 32];   // 28672 B
  __shared__ __align__(16) unsigned short XTl[2][72 * 32];     // 9216 B

  const int tid  = threadIdx.x;
  const int w    = tid >> 6;
  const int lane = tid & 63;
  const int l31  = lane & 31;
  const int hsel = lane >> 5;       // 0/1: k-subrow group
  const int kh   = w >> 1;          // k-half (0: k 0..31, 1: k 32..63)
  const int ph   = w & 1;           // px-half (0: px 0..31, 1: 32..63)

  // XCD-chunked bijective swizzle: 3584 blocks = 8 XCD x 448.
  const int wg = blockIdx.x;
  const int sw = (wg & 7) * 448 + (wg >> 3);
  const int ow0 = (sw & 3) * 64;
  const int ohb = ((sw >> 2) % 28) * ROWS;
  const int b   = sw / 112;

  // WT: linear async copy global->LDS (28 x 1024 B)
  for (int ch = w; ch < 28; ch += 4) {
    const unsigned short* g = WTg + ch * 512 + lane * 8;
    unsigned short* l = WTl + ch * 512;
    __builtin_amdgcn_global_load_lds((const __attribute__((address_space(1))) void*)g,
                                     (__attribute__((address_space(3))) void*)l, 16, 0, 0);
  }

  // m2 in 16 regs: k = kh*32 + 4*hsel + 8*g + (reg&3)
  f32x4 m2r[4];
  {
    const float* mp = m2inv + kh * 32 + 4 * hsel;
#pragma unroll
    for (int g = 0; g < 4; ++g) m2r[g] = *(const f32x4*)&mp[8 * g];
  }

  // zero pad lanes ci=21..31 in BOTH buffers (MFMA reads them; 0*NaN=NaN!)
  for (int idx = tid; idx < 2 * 72; idx += 256) {
    int bb = idx / 72, t = idx - 72 * bb;
    unsigned short* row = &XTl[bb][t * 32];
    const int m = (t >> 1) & 3;
    *(uint4*)&row[(3 ^ m) << 3] = (uint4){0, 0, 0, 0};   // ci 24..31
    const int b2 = (2 ^ m) << 3;                          // ci 21..23
    row[b2 + 5] = 0; row[b2 + 6] = 0; row[b2 + 7] = 0;
  }

  u64 s0[2];
  xt_issue(s0, xb, b, ohb, ow0, tid);
  xt_write(&XTl[0][0], s0, tid);
  asm volatile("s_waitcnt vmcnt(0) lgkmcnt(0)" ::: "memory");  // WT lds + XT writes
  __builtin_amdgcn_s_barrier();

  const int swzA = (l31 >> 1) & 3;  // A row = j*64 + kh*32 + l31 -> (row>>1)&3
  const int tB   = ph * 32 + l31;   // this lane's px within the 64-tile
  const int ow   = ow0 + tB;

#pragma unroll 1
  for (int r = 0; r < ROWS; ++r) {
    const int oh = ohb + r;
    const bool more = (r + 1 < ROWS);

    u64 sn[2];
    if (more) xt_issue(sn, xb, b, oh + 1, ow0, tid);   // loads fly over MFMAs

    const bool ok = (ow < OW) && (oh < OH);
    const float x2v = x2g[(size_t)(b * OH + (ok ? oh : 0)) * OW + (ok ? ow : 0)];

    const unsigned short* XT = &XTl[r & 1][0];
    f32x16 accA = {0.f,0.f,0.f,0.f,0.f,0.f,0.f,0.f,0.f,0.f,0.f,0.f,0.f,0.f,0.f,0.f};
    f32x16 accB = accA;

#pragma unroll
    for (int j = 0; j < KS; ++j) {
      const unsigned short* ar = WTl + (j * 64 + kh * 32 + l31) * 32;
      s16x8 aA = *(const s16x8*)&ar[(hsel ^ swzA) << 3];          // ci 0..15 slice
      s16x8 aB = *(const s16x8*)&ar[((2 + hsel) ^ swzA) << 3];    // ci 16..31 slice
      const int t = tB + j;
      const unsigned short* br = XT + t * 32;
      const int swzB = (t >> 1) & 3;
      s16x8 bA = *(const s16x8*)&br[(hsel ^ swzB) << 3];
      s16x8 bB = *(const s16x8*)&br[((2 + hsel) ^ swzB) << 3];
      accA = __builtin_amdgcn_mfma_f32_32x32x16_bf16(aA, bA, accA, 0, 0, 0);
      accB = __builtin_amdgcn_mfma_f32_32x32x16_bf16(aB, bB, accB, 0, 0, 0);
    }
    const f32x16 acc = accA + accB;

    // branchless store: invalid lanes go to dump (ks=0 collapses the k-stride).
    // C/D: col = lane&31 (=px), k = kh*32 + (reg&3) + 8*(reg>>2) + 4*hsel.
    float* ob = ok ? out + ((size_t)(b * NK + kh * 32) * OH + oh) * OW + ow : dump + tid;
    const size_t ks = ok ? (size_t)OHW : 0;
#pragma unroll
    for (int reg = 0; reg < 16; ++reg) {
      const int kk = (reg & 3) + 8 * (reg >> 2) + 4 * hsel;
      ob[(size_t)kk * ks] = (x2v - 2.0f * acc[reg]) * m2r[reg >> 2][reg & 3] + 1.0f;
    }

    if (more) {
      xt_write(&XTl[(r + 1) & 1][0], sn, tid);  // other-parity buffer: no read hazard
      asm volatile("s_waitcnt lgkmcnt(0)" ::: "memory");
      __builtin_amdgcn_s_barrier();             // single barrier per row
    }
  }
}

// ---------------- launch ----------------
extern "C" void kernel_launch(void* const* d_in, const int* in_sizes, int n_in,
                              void* d_out, int out_size, void* d_ws, size_t ws_size,
                              hipStream_t stream) {
  const float* x     = (const float*)d_in[0];   // [32,3,224,224]
  const float* memes = (const float*)d_in[1];   // [64,3,7,7]
  float* out = (float*)d_out;                   // [32,64,218,218]

  char* ws = (char*)d_ws;
  unsigned short* xb  = (unsigned short*)(ws);                 // 9,633,792 B
  float* t            = (float*)(ws + 9633792);                // 6,250,496 B
  float* x2           = (float*)(ws + 15884288);               // 6,083,072 B
  unsigned short* WTg = (unsigned short*)(ws + 21967360);      // 28,672 B
  float* m2inv        = (float*)(ws + 21996032);               // 256 B
  float* dump         = (float*)(ws + 21996544);               // scratch sink

  (void)in_sizes; (void)n_in; (void)out_size; (void)ws_size;

  k_prep_xrow<<<NB * IH, 256, 0, stream>>>(x, xb, t);
  k_colbox<<<(NB * OH * OW + 255) / 256, 256, 0, stream>>>(t, x2);
  k_prep_w<<<NK, 192, 0, stream>>>(memes, WTg, m2inv);

  // 3584 blocks = 4 ow-tiles x 28 oh-blocks x 32 b, flattened for XCD swizzle
  k_main<<<4 * 28 * NB, 256, 0, stream>>>(xb, x2, WTg, m2inv, out, dump);
}

// Round 8
// 158.105 us; speedup vs baseline: 2.0782x; 1.0069x over previous
//
#include <hip/hip_runtime.h>

#define NB 32
#define NC 3
#define NK 64
#define KS 7
#define IH 224
#define IW 224
#define OH 218
#define OW 218
#define OHW (OH * OW)
#define ROWS 8        // output rows per block (per-row double-buffered)

typedef float  f32x4  __attribute__((ext_vector_type(4)));
typedef float  f32x16 __attribute__((ext_vector_type(16)));
typedef short  s16x8  __attribute__((ext_vector_type(8)));
typedef unsigned long long u64;

static __device__ __forceinline__ unsigned short f2bf(float f) {
  unsigned int u = __float_as_uint(f);
  u += 0x7FFFu + ((u >> 16) & 1u);
  return (unsigned short)(u >> 16);
}

// XOR block-swizzle on a 32-u16 (64 B) row: 16B-block ^= (row>>1)&3.
static __device__ __forceinline__ int swz(int r, int ci) {
  return (((ci >> 3) ^ ((r >> 1) & 3)) << 3) | (ci & 7);
}

// ---------------- prep kernels ----------------

// fused: x -> bf16, s = sum_c x^2 (LDS), row box -> t[b][h][ow]
__global__ void k_prep_xrow(const float* __restrict__ x, unsigned short* __restrict__ xb,
                            float* __restrict__ t) {
  __shared__ float s_lds[IW];
  const int n  = blockIdx.x;          // NB*IH
  const int b  = n / IH;
  const int h  = n - b * IH;
  const int px = threadIdx.x;
  if (px < IW) {
    float acc = 0.f;
#pragma unroll
    for (int c = 0; c < NC; ++c) {
      size_t idx = ((size_t)(b * NC + c) * IH + h) * IW + px;
      float v = x[idx];
      xb[idx] = f2bf(v);
      acc += v * v;
    }
    s_lds[px] = acc;
  }
  __syncthreads();
  if (px < OW) {
    float acc = 0.f;
#pragma unroll
    for (int j = 0; j < KS; ++j) acc += s_lds[px + j];
    t[(size_t)(b * IH + h) * OW + px] = acc;
  }
}

// WTg[row=j*64+k][ci'(swizzled, 32)] = bf16(memes[k][c][i][j]); zeros at ci>=21.
__global__ void k_prep_w(const float* __restrict__ memes, unsigned short* __restrict__ WTg,
                         float* __restrict__ m2inv) {
  __shared__ float red[3];
  const int k = blockIdx.x, t = threadIdx.x;
  float v = 0.f;
  if (t < 147) v = memes[k * 147 + t];
  float s = v * v;
#pragma unroll
  for (int sh = 32; sh > 0; sh >>= 1) s += __shfl_down(s, sh, 64);
  if ((t & 63) == 0) red[t >> 6] = s;
  __syncthreads();
  if (t == 0) m2inv[k] = 1.0f / (red[0] + red[1] + red[2]);
  if (t < 147) {
    int c = t / 49, rem = t - 49 * c, i = rem / 7, j = rem - 7 * i;
    int row = j * NK + k;
    WTg[row * 32 + swz(row, c * 7 + i)] = f2bf(v);
  }
  for (int idx = t; idx < 7 * 11; idx += 192) {
    int j = idx / 11, ci = 21 + (idx - 11 * j);
    int row = j * NK + k;
    WTg[row * 32 + swz(row, ci)] = 0;
  }
}

// ---------------- per-row staging (issue-early / write-late) ----------------
// One row = 21 ci x 18 tq (u64 = 4 px) = 378 slots over 256 threads * 2.
static __device__ __forceinline__ void xt_issue(u64 v[2],
    const unsigned short* __restrict__ xb, int b, int oh, int ow0, int tid) {
#pragma unroll
  for (int m = 0; m < 2; ++m) {
    int idx = tid + 256 * m;
    u64 val = 0;
    if (idx < 378) {
      int tq = idx % 18;
      int ci = idx / 18;
      int c  = ci / 7;
      int i  = ci - 7 * c;
      // unguarded: overreads stay inside ws (finite bits), feed only masked lanes
      val = *(const u64*)&xb[((size_t)(b * NC + c) * IH + oh + i) * IW + ow0 + 4 * tq];
    }
    v[m] = val;
  }
}

static __device__ __forceinline__ void xt_write(unsigned short* __restrict__ XT,
    const u64 v[2], int tid) {
#pragma unroll
  for (int m = 0; m < 2; ++m) {
    int idx = tid + 256 * m;
    if (idx < 378) {
      int tq = idx % 18;
      int ci = idx / 18;
#pragma unroll
      for (int e = 0; e < 4; ++e) {
        int t = 4 * tq + e;
        XT[t * 32 + swz(t, ci)] = (unsigned short)(v[m] >> (16 * e));
      }
    }
  }
}

// ---------------- main MFMA kernel (32x32x16) ----------------
// Block: 256 thr (4 waves), 4 blocks/CU. Wave = (k-half, px-half) quadrant.
// Store instr = 2 full 128B lines. Exec-masked stores (no dump traffic).
// x2 computed on the fly from t (colbox fused). XCD-chunked block swizzle.
__global__ __launch_bounds__(256, 4) void k_main(
    const unsigned short* __restrict__ xb, const float* __restrict__ tg,
    const unsigned short* __restrict__ WTg, const float* __restrict__ m2inv,
    float* __restrict__ out) {
  __shared__ __align__(16) unsigned short WTl[KS * NK * 32];   // 28672 B
  __shared__ __align__(16) unsigned short XTl[2][72 * 32];     // 9216 B

  const int tid  = threadIdx.x;
  const int w    = tid >> 6;
  const int lane = tid & 63;
  const int l31  = lane & 31;
  const int hsel = lane >> 5;       // 0/1: k-subrow group
  const int kh   = w >> 1;          // k-half (0: k 0..31, 1: k 32..63)
  const int ph   = w & 1;           // px-half (0: px 0..31, 1: 32..63)

  // XCD-chunked bijective swizzle: 3584 blocks = 8 XCD x 448.
  const int wg = blockIdx.x;
  const int sw = (wg & 7) * 448 + (wg >> 3);
  const int ow0 = (sw & 3) * 64;
  const int ohb = ((sw >> 2) % 28) * ROWS;
  const int b   = sw / 112;

  // WT: linear async copy global->LDS (28 x 1024 B)
  for (int ch = w; ch < 28; ch += 4) {
    const unsigned short* g = WTg + ch * 512 + lane * 8;
    unsigned short* l = WTl + ch * 512;
    __builtin_amdgcn_global_load_lds((const __attribute__((address_space(1))) void*)g,
                                     (__attribute__((address_space(3))) void*)l, 16, 0, 0);
  }

  // m2 in 16 regs: k = kh*32 + 4*hsel + 8*g + (reg&3)
  f32x4 m2r[4];
  {
    const float* mp = m2inv + kh * 32 + 4 * hsel;
#pragma unroll
    for (int g = 0; g < 4; ++g) m2r[g] = *(const f32x4*)&mp[8 * g];
  }

  // zero pad lanes ci=21..31 in BOTH buffers (MFMA reads them; 0*NaN=NaN!)
  for (int idx = tid; idx < 2 * 72; idx += 256) {
    int bb = idx / 72, t = idx - 72 * bb;
    unsigned short* row = &XTl[bb][t * 32];
    const int m = (t >> 1) & 3;
    *(uint4*)&row[(3 ^ m) << 3] = (uint4){0, 0, 0, 0};   // ci 24..31
    const int b2 = (2 ^ m) << 3;                          // ci 21..23
    row[b2 + 5] = 0; row[b2 + 6] = 0; row[b2 + 7] = 0;
  }

  u64 s0[2];
  xt_issue(s0, xb, b, ohb, ow0, tid);
  xt_write(&XTl[0][0], s0, tid);
  asm volatile("s_waitcnt vmcnt(0) lgkmcnt(0)" ::: "memory");  // WT lds + XT writes
  __builtin_amdgcn_s_barrier();

  const int swzA = (l31 >> 1) & 3;  // A row = j*64 + kh*32 + l31 -> (row>>1)&3
  const int tB   = ph * 32 + l31;   // this lane's px within the 64-tile
  const int ow   = ow0 + tB;

#pragma unroll 1
  for (int r = 0; r < ROWS; ++r) {
    const int oh = ohb + r;
    const bool more = (r + 1 < ROWS);

    u64 sn[2];
    if (more) xt_issue(sn, xb, b, oh + 1, ow0, tid);   // loads fly over MFMAs

    const bool ok = (ow < OW) && (oh < OH);

    // x2 on the fly (colbox fused): 7 L2-hot loads, issued early, masked lanes skip
    float x2v = 0.f;
    if (ok) {
      const float* tp = tg + ((size_t)b * IH + oh) * OW + ow;
#pragma unroll
      for (int i = 0; i < KS; ++i) x2v += tp[i * OW];
    }

    const unsigned short* XT = &XTl[r & 1][0];
    f32x16 accA = {0.f,0.f,0.f,0.f,0.f,0.f,0.f,0.f,0.f,0.f,0.f,0.f,0.f,0.f,0.f,0.f};
    f32x16 accB = accA;

#pragma unroll
    for (int j = 0; j < KS; ++j) {
      const unsigned short* ar = WTl + (j * 64 + kh * 32 + l31) * 32;
      s16x8 aA = *(const s16x8*)&ar[(hsel ^ swzA) << 3];          // ci 0..15 slice
      s16x8 aB = *(const s16x8*)&ar[((2 + hsel) ^ swzA) << 3];    // ci 16..31 slice
      const int t = tB + j;
      const unsigned short* br = XT + t * 32;
      const int swzB = (t >> 1) & 3;
      s16x8 bA = *(const s16x8*)&br[(hsel ^ swzB) << 3];
      s16x8 bB = *(const s16x8*)&br[((2 + hsel) ^ swzB) << 3];
      accA = __builtin_amdgcn_mfma_f32_32x32x16_bf16(aA, bA, accA, 0, 0, 0);
      accB = __builtin_amdgcn_mfma_f32_32x32x16_bf16(aB, bB, accB, 0, 0, 0);
    }
    const f32x16 acc = accA + accB;

    // exec-masked stores: invalid lanes are simply masked off (free).
    // C/D: col = lane&31 (=px), k = kh*32 + (reg&3) + 8*(reg>>2) + 4*hsel.
    if (ok) {
      float* ob = out + ((size_t)(b * NK + kh * 32) * OH + oh) * OW + ow;
#pragma unroll
      for (int reg = 0; reg < 16; ++reg) {
        const int kk = (reg & 3) + 8 * (reg >> 2) + 4 * hsel;
        ob[(size_t)kk * OHW] = (x2v - 2.0f * acc[reg]) * m2r[reg >> 2][reg & 3] + 1.0f;
      }
    }

    if (more) {
      xt_write(&XTl[(r + 1) & 1][0], sn, tid);  // other-parity buffer: no read hazard
      asm volatile("s_waitcnt lgkmcnt(0)" ::: "memory");
      __builtin_amdgcn_s_barrier();             // single barrier per row
    }
  }
}

// ---------------- launch ----------------
extern "C" void kernel_launch(void* const* d_in, const int* in_sizes, int n_in,
                              void* d_out, int out_size, void* d_ws, size_t ws_size,
                              hipStream_t stream) {
  const float* x     = (const float*)d_in[0];   // [32,3,224,224]
  const float* memes = (const float*)d_in[1];   // [64,3,7,7]
  float* out = (float*)d_out;                   // [32,64,218,218]

  char* ws = (char*)d_ws;
  unsigned short* xb  = (unsigned short*)(ws);                 // 9,633,792 B
  float* t            = (float*)(ws + 9633792);                // 6,250,496 B
  unsigned short* WTg = (unsigned short*)(ws + 15884288);      // 28,672 B
  float* m2inv        = (float*)(ws + 15912960);               // 256 B

  (void)in_sizes; (void)n_in; (void)out_size; (void)ws_size;

  k_prep_xrow<<<NB * IH, 256, 0, stream>>>(x, xb, t);
  k_prep_w<<<NK, 192, 0, stream>>>(memes, WTg, m2inv);

  // 3584 blocks = 4 ow-tiles x 28 oh-blocks x 32 b, flattened for XCD swizzle
  k_main<<<4 * 28 * NB, 256, 0, stream>>>(xb, t, WTg, m2inv, out);
}